// Round 3
// baseline (721.899 us; speedup 1.0000x reference)
//
#include <hip/hip_runtime.h>
#include <hip/hip_bf16.h>
#include <math.h>

#define N_NODES 50000
#define N_EDGES 800000
#define GK 256

typedef unsigned short US;
typedef __attribute__((ext_vector_type(8))) short short8;
typedef __attribute__((ext_vector_type(4))) float floatx4;
typedef __attribute__((address_space(1))) const void* gptr_t;
typedef __attribute__((address_space(3))) void* lptr_t;

static __device__ __forceinline__ float bflo(unsigned int u) {
  union { unsigned int i; float f; } c; c.i = u << 16; return c.f;
}
static __device__ __forceinline__ float bfhi(unsigned int u) {
  union { unsigned int i; float f; } c; c.i = u & 0xffff0000u; return c.f;
}
static __device__ __forceinline__ float bf2f(US u) {
  union { unsigned int i; float f; } c; c.i = ((unsigned int)u) << 16; return c.f;
}
static __device__ __forceinline__ US f2bf(float f) {  // round-to-nearest-even
  union { float f; unsigned int i; } c; c.f = f;
  unsigned int x = c.i;
  return (US)((x + 0x7fffu + ((x >> 16) & 1u)) >> 16);
}

// ----------------- preprocessing -----------------
// Wt1: old layout [n][k] (layer-1 gemm unchanged).
// Wt2c/Wt3c: K-CHUNKED layout [kc][n][8] so fused kernels can stage B with
// linear global_load_lds AND read LDS conflict-free ([kc][n][8] -> lanes of
// consecutive n are contiguous).

__global__ void pre0_kernel(const int* __restrict__ col, int* __restrict__ cnt,
                            const float* __restrict__ x, US* __restrict__ xb,
                            const float* __restrict__ W1, const float* __restrict__ W2,
                            const float* __restrict__ W3,
                            US* __restrict__ Wt1, US* __restrict__ Wt2c,
                            US* __restrict__ Wt3c) {
  int gt = blockIdx.x * 256 + threadIdx.x;
  int gs = gridDim.x * 256;
  for (int e = gt; e < N_EDGES; e += gs) atomicAdd(&cnt[col[e]], 1);
  for (int i = gt; i < N_NODES * 64; i += gs) {   // x: 12.8M elems / 4
    float4 v = *(const float4*)(x + (size_t)i * 4);
    US o[4] = { f2bf(v.x), f2bf(v.y), f2bf(v.z), f2bf(v.w) };
    *(ushort4*)(xb + (size_t)i * 4) = *(ushort4*)o;
  }
  for (int idx = gt; idx < 147456; idx += gs) {
    if (idx < 65536) {
      int k = idx >> 8, n = idx & 255;
      Wt1[n * 256 + k] = f2bf(W1[idx]);
    } else if (idx < 131072) {
      int i = idx - 65536, k = i >> 8, n = i & 255;
      Wt2c[(k >> 3) * 2048 + n * 8 + (k & 7)] = f2bf(W2[i]);
    } else {
      int i = idx - 131072, k = i >> 6, n = i & 63;
      Wt3c[(k >> 3) * 512 + n * 8 + (k & 7)] = f2bf(W3[i]);
    }
  }
}

__global__ void scan_block_kernel(const int* __restrict__ in, int* __restrict__ out,
                                  int* __restrict__ bsums, float* __restrict__ dinv, int n) {
  __shared__ int s[256];
  int gid = blockIdx.x * 256 + threadIdx.x;
  int v = (gid < n) ? in[gid] : 0;
  if (gid < n) dinv[gid] = 1.0f / sqrtf((float)(v + 1));  // +1 self-loop
  s[threadIdx.x] = v;
  __syncthreads();
  for (int off = 1; off < 256; off <<= 1) {
    int t = (threadIdx.x >= off) ? s[threadIdx.x - off] : 0;
    __syncthreads();
    s[threadIdx.x] += t;
    __syncthreads();
  }
  if (gid < n) out[gid] = s[threadIdx.x] - v;  // exclusive
  if (threadIdx.x == 255) bsums[blockIdx.x] = s[255];
}

__global__ void scan_top_kernel(int* __restrict__ bsums, int n) {
  __shared__ int s[256];
  int v = (threadIdx.x < n) ? bsums[threadIdx.x] : 0;
  s[threadIdx.x] = v;
  __syncthreads();
  for (int off = 1; off < 256; off <<= 1) {
    int t = (threadIdx.x >= off) ? s[threadIdx.x - off] : 0;
    __syncthreads();
    s[threadIdx.x] += t;
    __syncthreads();
  }
  if (threadIdx.x < n) bsums[threadIdx.x] = s[threadIdx.x] - v;
}

__global__ void scan_add_kernel(int* __restrict__ row_ptr, int* __restrict__ fill,
                                const int* __restrict__ bsums, int n) {
  int gid = blockIdx.x * 256 + threadIdx.x;
  if (gid < n) {
    int v = row_ptr[gid] + bsums[blockIdx.x];
    row_ptr[gid] = v;
    fill[gid] = v;
  }
}

__global__ void fill_kernel(const int* __restrict__ row, const int* __restrict__ col,
                            int* __restrict__ fill, int2* __restrict__ srcs2,
                            const float* __restrict__ dinv, int E) {
  int e = blockIdx.x * blockDim.x + threadIdx.x;
  if (e < E) {
    int d = col[e];
    int r = row[e];
    int pos = atomicAdd(&fill[d], 1);
    srcs2[pos] = make_int2(r, __float_as_int(dinv[r]));
  }
}

// ----------------- shared gather body (256-dim, relu, bias) -----------------
// One wave gathers one node row. Pair-edge uint4 gathers (lanes 0-31 = edge i,
// 32-63 = edge i+1), unroll 8. Result: lanes 0..31 hold bf16-packed o[8] for
// dims [ (lane&31)*8, +8 ).

static __device__ __forceinline__ void gather256_row(
    const US* __restrict__ t, int j, int lane,
    const int* __restrict__ row_ptr, const int* __restrict__ cnt,
    const int2* __restrict__ srcs2, const float* __restrict__ dinv,
    const float* __restrict__ bias, US* __restrict__ o) {
  int h = lane & 31;
  int eidx = lane >> 5;
  int base = h * 8;
  int start = row_ptr[j];
  int n = cnt[j];
  float a[8];
#pragma unroll
  for (int k = 0; k < 8; ++k) a[k] = 0.f;

  int i = 0;
  for (; i + 7 < n; i += 8) {
    int2 e0 = srcs2[start + i + 0 + eidx];
    int2 e1 = srcs2[start + i + 2 + eidx];
    int2 e2 = srcs2[start + i + 4 + eidx];
    int2 e3 = srcs2[start + i + 6 + eidx];
    uint4 v0 = *(const uint4*)(t + (size_t)e0.x * 256 + base);
    uint4 v1 = *(const uint4*)(t + (size_t)e1.x * 256 + base);
    uint4 v2 = *(const uint4*)(t + (size_t)e2.x * 256 + base);
    uint4 v3 = *(const uint4*)(t + (size_t)e3.x * 256 + base);
    float w0 = __int_as_float(e0.y), w1 = __int_as_float(e1.y);
    float w2 = __int_as_float(e2.y), w3 = __int_as_float(e3.y);
    a[0] += bflo(v0.x) * w0; a[1] += bfhi(v0.x) * w0;
    a[2] += bflo(v0.y) * w0; a[3] += bfhi(v0.y) * w0;
    a[4] += bflo(v0.z) * w0; a[5] += bfhi(v0.z) * w0;
    a[6] += bflo(v0.w) * w0; a[7] += bfhi(v0.w) * w0;
    a[0] += bflo(v1.x) * w1; a[1] += bfhi(v1.x) * w1;
    a[2] += bflo(v1.y) * w1; a[3] += bfhi(v1.y) * w1;
    a[4] += bflo(v1.z) * w1; a[5] += bfhi(v1.z) * w1;
    a[6] += bflo(v1.w) * w1; a[7] += bfhi(v1.w) * w1;
    a[0] += bflo(v2.x) * w2; a[1] += bfhi(v2.x) * w2;
    a[2] += bflo(v2.y) * w2; a[3] += bfhi(v2.y) * w2;
    a[4] += bflo(v2.z) * w2; a[5] += bfhi(v2.z) * w2;
    a[6] += bflo(v2.w) * w2; a[7] += bfhi(v2.w) * w2;
    a[0] += bflo(v3.x) * w3; a[1] += bfhi(v3.x) * w3;
    a[2] += bflo(v3.y) * w3; a[3] += bfhi(v3.y) * w3;
    a[4] += bflo(v3.z) * w3; a[5] += bfhi(v3.z) * w3;
    a[6] += bflo(v3.w) * w3; a[7] += bfhi(v3.w) * w3;
  }
  for (; i < n; i += 2) {
    int idx = i + eidx;
    int cl = min(idx, n - 1);
    int2 e = srcs2[start + cl];
    float w = (idx < n) ? __int_as_float(e.y) : 0.f;
    uint4 v = *(const uint4*)(t + (size_t)e.x * 256 + base);
    a[0] += bflo(v.x) * w; a[1] += bfhi(v.x) * w;
    a[2] += bflo(v.y) * w; a[3] += bfhi(v.y) * w;
    a[4] += bflo(v.z) * w; a[5] += bfhi(v.z) * w;
    a[6] += bflo(v.w) * w; a[7] += bfhi(v.w) * w;
  }
#pragma unroll
  for (int k = 0; k < 8; ++k) a[k] += __shfl_xor(a[k], 32, 64);

  float dj = dinv[j];
  uint4 vj = *(const uint4*)(t + (size_t)j * 256 + base);
  float4 bv0 = *(const float4*)(bias + base);
  float4 bv1 = *(const float4*)(bias + base + 4);
  float r[8];
  r[0] = (a[0] + bflo(vj.x) * dj) * dj + bv0.x;
  r[1] = (a[1] + bfhi(vj.x) * dj) * dj + bv0.y;
  r[2] = (a[2] + bflo(vj.y) * dj) * dj + bv0.z;
  r[3] = (a[3] + bfhi(vj.y) * dj) * dj + bv0.w;
  r[4] = (a[4] + bflo(vj.z) * dj) * dj + bv1.x;
  r[5] = (a[5] + bfhi(vj.z) * dj) * dj + bv1.y;
  r[6] = (a[6] + bflo(vj.w) * dj) * dj + bv1.z;
  r[7] = (a[7] + bfhi(vj.w) * dj) * dj + bv1.w;
#pragma unroll
  for (int k = 0; k < 8; ++k) {
    r[k] = fmaxf(r[k], 0.f);                 // relu (all fused-agg layers)
    o[k] = f2bf(r[k]);
  }
}

// ----------------- fused agg + GEMM256: bout[j,:] = relu(agg(t)[j]+bias) @ W -----------------
// Block = 32 nodes. Phase 1: gather rows into LDS A-tile (swizzled ds_write).
// Phase 2: stream chunked weight via global_load_lds, counted-vmcnt dbuf, MFMA.
// LDS 48KB -> 3 blocks/CU (12 waves) so other blocks' gathers overlap MFMA.

__global__ __launch_bounds__(256) void fused_ag256_kernel(
    const US* __restrict__ t, US* __restrict__ bout,
    const int* __restrict__ row_ptr, const int* __restrict__ cnt,
    const int2* __restrict__ srcs2, const float* __restrict__ dinv,
    const float* __restrict__ bias, const US* __restrict__ Wtc, int M) {
  __shared__ __align__(16) US shm[24576];   // As [0,8192)  Bs dbuf [8192,24576)
  US* As = shm;
  US* Bs = shm + 8192;
  int tid = threadIdx.x;
  int j0 = blockIdx.x * 32;
  int lane = tid & 63;
  int w = tid >> 6;

  // B step-0 prefetch (completes during gather; disjoint LDS region)
  auto issueB = [&](int st, int b) {
#pragma unroll
    for (int it = 0; it < 4; ++it) {
      const US* g = Wtc + st * 8192 + it * 2048 + tid * 8;
      __builtin_amdgcn_global_load_lds((gptr_t)(const void*)g,
          (lptr_t)(void*)&Bs[b * 8192 + it * 2048 + tid * 8], 16, 0, 0);
    }
  };
  issueB(0, 0);

  // ---- phase 1: gather 32 node rows into As ----
  {
    int h = lane & 31;
    US o[8];
#pragma unroll 1
    for (int q = 0; q < 8; ++q) {
      int jl = q * 4 + w;
      int j = j0 + jl;
      if (j < M) {
        gather256_row(t, j, lane, row_ptr, cnt, srcs2, dinv, bias, o);
        if (lane < 32) {
          int pos = jl * 256 + ((h ^ (jl & 7)) << 3);   // XOR-swizzled chunk
          *(uint4*)&As[pos] = *(const uint4*)o;
        }
      }
    }
  }
  asm volatile("s_waitcnt lgkmcnt(0)" ::: "memory");   // As writes visible
  __builtin_amdgcn_sched_barrier(0);
  __builtin_amdgcn_s_barrier();                        // raw: step-0 B stays in flight

  // ---- phase 2: GEMM 32x256 = As @ Wtc^T ----
  int wc = w * 64;
  int lm = lane & 15, lk = lane >> 4;
  floatx4 zero = {0.f, 0.f, 0.f, 0.f};
  floatx4 acc[2][4];
#pragma unroll
  for (int i = 0; i < 2; ++i)
#pragma unroll
    for (int j = 0; j < 4; ++j) acc[i][j] = zero;

#pragma unroll
  for (int st = 0; st < 8; ++st) {
    if (st < 7) {
      issueB(st + 1, (st + 1) & 1);
      asm volatile("s_waitcnt vmcnt(4)" ::: "memory");
    } else {
      asm volatile("s_waitcnt vmcnt(0)" ::: "memory");
    }
    __builtin_amdgcn_sched_barrier(0);
    __builtin_amdgcn_s_barrier();
    const US* Bsb = Bs + (st & 1) * 8192;
    short8 af[2], bfr[4];
#pragma unroll
    for (int i = 0; i < 2; ++i) {
      int row = i * 16 + lm;
      int c = (st * 4 + lk) ^ (row & 7);
      af[i] = *(const short8*)&As[row * 256 + c * 8];
    }
#pragma unroll
    for (int j = 0; j < 4; ++j)
      bfr[j] = *(const short8*)&Bsb[lk * 2048 + (wc + j * 16 + lm) * 8];
#pragma unroll
    for (int i = 0; i < 2; ++i)
#pragma unroll
      for (int j = 0; j < 4; ++j)
        acc[i][j] = __builtin_amdgcn_mfma_f32_16x16x32_bf16(af[i], bfr[j], acc[i][j], 0, 0, 0);
    __builtin_amdgcn_s_barrier();
  }

  // epilogue: Cs 32x272 (LDS reuse) -> coalesced 16B stores
  {
    constexpr int LDC = 272;
    US* Cs = shm;                            // 8704 US <= 24576
#pragma unroll
    for (int i = 0; i < 2; ++i)
#pragma unroll
      for (int j = 0; j < 4; ++j) {
        int colg = wc + j * 16 + lm;
#pragma unroll
        for (int r = 0; r < 4; ++r)
          Cs[(i * 16 + lk * 4 + r) * LDC + colg] = f2bf(acc[i][j][r]);
      }
    __syncthreads();
#pragma unroll
    for (int c = 0; c < 4; ++c) {            // 1024 = 32 rows x 32 chunks
      int idx = tid + c * 256;
      int row = idx >> 5;
      int ch = idx & 31;
      uint4 v = *(const uint4*)&Cs[row * LDC + ch * 8];
      if (j0 + row < M) *(uint4*)&bout[(size_t)(j0 + row) * 256 + ch * 8] = v;
    }
  }
}

// ----------------- fused agg + GEMM64: bout[j,0:64] = relu(agg(t)[j]+bias) @ W3 -----------------

__global__ __launch_bounds__(256) void fused_ag64_kernel(
    const US* __restrict__ t, US* __restrict__ bout,
    const int* __restrict__ row_ptr, const int* __restrict__ cnt,
    const int2* __restrict__ srcs2, const float* __restrict__ dinv,
    const float* __restrict__ bias, const US* __restrict__ Wtc, int M) {
  __shared__ __align__(16) US shm[12288];   // As [0,8192)  Bs dbuf [8192,12288)
  US* As = shm;
  US* Bs = shm + 8192;
  int tid = threadIdx.x;
  int j0 = blockIdx.x * 32;
  int lane = tid & 63;
  int w = tid >> 6;

  auto issueB = [&](int st, int b) {
    const US* g = Wtc + st * 2048 + tid * 8;
    __builtin_amdgcn_global_load_lds((gptr_t)(const void*)g,
        (lptr_t)(void*)&Bs[b * 2048 + tid * 8], 16, 0, 0);
  };
  issueB(0, 0);

  {
    int h = lane & 31;
    US o[8];
#pragma unroll 1
    for (int q = 0; q < 8; ++q) {
      int jl = q * 4 + w;
      int j = j0 + jl;
      if (j < M) {
        gather256_row(t, j, lane, row_ptr, cnt, srcs2, dinv, bias, o);
        if (lane < 32) {
          int pos = jl * 256 + ((h ^ (jl & 7)) << 3);
          *(uint4*)&As[pos] = *(const uint4*)o;
        }
      }
    }
  }
  asm volatile("s_waitcnt lgkmcnt(0)" ::: "memory");
  __builtin_amdgcn_sched_barrier(0);
  __builtin_amdgcn_s_barrier();

  int lm = lane & 15, lk = lane >> 4;
  floatx4 zero = {0.f, 0.f, 0.f, 0.f};
  floatx4 acc[2] = {zero, zero};

#pragma unroll
  for (int st = 0; st < 8; ++st) {
    if (st < 7) {
      issueB(st + 1, (st + 1) & 1);
      asm volatile("s_waitcnt vmcnt(1)" ::: "memory");
    } else {
      asm volatile("s_waitcnt vmcnt(0)" ::: "memory");
    }
    __builtin_amdgcn_sched_barrier(0);
    __builtin_amdgcn_s_barrier();
    const US* Bsb = Bs + (st & 1) * 2048;
    short8 af[2];
#pragma unroll
    for (int i = 0; i < 2; ++i) {
      int row = i * 16 + lm;
      int c = (st * 4 + lk) ^ (row & 7);
      af[i] = *(const short8*)&As[row * 256 + c * 8];
    }
    short8 bfr = *(const short8*)&Bsb[lk * 512 + (w * 16 + lm) * 8];
#pragma unroll
    for (int i = 0; i < 2; ++i)
      acc[i] = __builtin_amdgcn_mfma_f32_16x16x32_bf16(af[i], bfr, acc[i], 0, 0, 0);
    __builtin_amdgcn_s_barrier();
  }

  // epilogue: Cs 32x72 -> coalesced stores (wave w owns cols w*16..w*16+15)
  {
    constexpr int LDC = 72;
    US* Cs = shm;                            // 2304 US
#pragma unroll
    for (int i = 0; i < 2; ++i) {
      int colg = w * 16 + lm;
#pragma unroll
      for (int r = 0; r < 4; ++r)
        Cs[(i * 16 + lk * 4 + r) * LDC + colg] = f2bf(acc[i][r]);
    }
    __syncthreads();
    {                                        // 256 slots = 32 rows x 8 chunks
      int row = tid >> 3;
      int ch = tid & 7;
      uint4 v = *(const uint4*)&Cs[row * LDC + ch * 8];
      if (j0 + row < M) *(uint4*)&bout[(size_t)(j0 + row) * 64 + ch * 8] = v;
    }
  }
}

// ----------------- fused agg64 + final dense + sigmoid -----------------
// h6 = agg(G6)+b3 (no relu, f32), out = sigmoid(h6 @ W4 + b4). W4 f32 in LDS.
// Block = 16 nodes (4 per wave); per node: 64-dim gather, stage h to LDS,
// 64-lane matvec against W4.

__global__ __launch_bounds__(256) void aggfinal_kernel(
    const US* __restrict__ t, float* __restrict__ out,
    const int* __restrict__ row_ptr, const int* __restrict__ cnt,
    const int2* __restrict__ srcs2, const float* __restrict__ dinv,
    const float* __restrict__ b3, const float* __restrict__ W4,
    const float* __restrict__ b4, int M) {
  __shared__ float W4s[4096];
  __shared__ float b4s[64];
  __shared__ float hbuf[4][64];
  int tid = threadIdx.x;
#pragma unroll
  for (int it = 0; it < 16; ++it) W4s[it * 256 + tid] = W4[it * 256 + tid];
  if (tid < 64) b4s[tid] = b4[tid];
  __syncthreads();

  int wv = tid >> 6, lane = tid & 63;
  int g = lane & 15, eidx = lane >> 4;
  int base = g * 4;
#pragma unroll 1
  for (int q = 0; q < 4; ++q) {
    int j = blockIdx.x * 16 + wv * 4 + q;
    if (j >= M) break;
    int start = row_ptr[j];
    int n = cnt[j];
    float a[4] = {0.f, 0.f, 0.f, 0.f};
    int i = 0;
    for (; i + 7 < n; i += 8) {
      int2 e0 = srcs2[start + i + eidx];
      int2 e1 = srcs2[start + i + 4 + eidx];
      uint2 v0 = *(const uint2*)(t + (size_t)e0.x * 64 + base);
      uint2 v1 = *(const uint2*)(t + (size_t)e1.x * 64 + base);
      float w0 = __int_as_float(e0.y), w1 = __int_as_float(e1.y);
      a[0] += bflo(v0.x) * w0; a[1] += bfhi(v0.x) * w0;
      a[2] += bflo(v0.y) * w0; a[3] += bfhi(v0.y) * w0;
      a[0] += bflo(v1.x) * w1; a[1] += bfhi(v1.x) * w1;
      a[2] += bflo(v1.y) * w1; a[3] += bfhi(v1.y) * w1;
    }
    for (; i < n; i += 4) {
      int idx = i + eidx;
      int cl = min(idx, n - 1);
      int2 e = srcs2[start + cl];
      float w0 = (idx < n) ? __int_as_float(e.y) : 0.f;
      uint2 v = *(const uint2*)(t + (size_t)e.x * 64 + base);
      a[0] += bflo(v.x) * w0; a[1] += bfhi(v.x) * w0;
      a[2] += bflo(v.y) * w0; a[3] += bfhi(v.y) * w0;
    }
#pragma unroll
    for (int k = 0; k < 4; ++k) {
      a[k] += __shfl_xor(a[k], 16, 64);
      a[k] += __shfl_xor(a[k], 32, 64);
    }
    float dj = dinv[j];
    uint2 vj = *(const uint2*)(t + (size_t)j * 64 + base);
    float4 bv = *(const float4*)(b3 + base);
    float h0 = (a[0] + bflo(vj.x) * dj) * dj + bv.x;
    float h1 = (a[1] + bfhi(vj.x) * dj) * dj + bv.y;
    float h2 = (a[2] + bflo(vj.y) * dj) * dj + bv.z;
    float h3 = (a[3] + bfhi(vj.y) * dj) * dj + bv.w;
    if (lane < 16) {
      float4 hv = make_float4(h0, h1, h2, h3);
      *(float4*)&hbuf[wv][base] = hv;
    }
    asm volatile("s_waitcnt lgkmcnt(0)" ::: "memory");
    float acc = b4s[lane];
#pragma unroll 8
    for (int k = 0; k < 64; ++k) acc += hbuf[wv][k] * W4s[k * 64 + lane];
    out[(size_t)j * 64 + lane] = 1.0f / (1.0f + expf(-acc));
  }
}

// ----------------- gemm256 (layer 1 only): C[M,256] = A[M,256] @ Wt[256,256]^T -----------------
// R2 pipeline kept: dbuf LDS + counted vmcnt + raw barriers.

__global__ __launch_bounds__(256) void gemm256_kernel(
    const US* __restrict__ A, const US* __restrict__ Wt,
    US* __restrict__ C, int M) {
  __shared__ __align__(16) US shm[40960];      // 80KB
  int tid = threadIdx.x;
  int bm = blockIdx.x * 64;
  int lane = tid & 63;
  int w = tid >> 6;
  int wc = w * 64;
  int lm = lane & 15, lk = lane >> 4;
  int lr = lane >> 3, lc = lane & 7;
  int gc = lc ^ lr;

  floatx4 zero = {0.f, 0.f, 0.f, 0.f};
  floatx4 acc[4][4];
#pragma unroll
  for (int i = 0; i < 4; ++i)
#pragma unroll
    for (int j = 0; j < 4; ++j) acc[i][j] = zero;

  auto issue = [&](int k, int b) {
    int k0 = k * 64;
    US* As = shm + b * 4096;
    US* Bs = shm + 8192 + b * 16384;
#pragma unroll
    for (int i = 0; i < 2; ++i) {
      int rbase = i * 32 + w * 8;
      int r = min(bm + rbase + lr, M - 1);
      const US* ga = A + (size_t)r * GK + k0 + gc * 8;
      __builtin_amdgcn_global_load_lds((gptr_t)(const void*)ga,
                                       (lptr_t)(void*)&As[rbase * 64], 16, 0, 0);
    }
#pragma unroll
    for (int i = 0; i < 8; ++i) {
      int rbase = i * 32 + w * 8;
      int r = rbase + lr;
      const US* gb = Wt + (size_t)r * GK + k0 + gc * 8;
      __builtin_amdgcn_global_load_lds((gptr_t)(const void*)gb,
                                       (lptr_t)(void*)&Bs[rbase * 64], 16, 0, 0);
    }
  };

  issue(0, 0);
#pragma unroll
  for (int k = 0; k < 4; ++k) {
    if (k < 3) {
      issue(k + 1, (k + 1) & 1);
      asm volatile("s_waitcnt vmcnt(10)" ::: "memory");
    } else {
      asm volatile("s_waitcnt vmcnt(0)" ::: "memory");
    }
    __builtin_amdgcn_sched_barrier(0);
    __builtin_amdgcn_s_barrier();
    const US* As = shm + (k & 1) * 4096;
    const US* Bs = shm + 8192 + (k & 1) * 16384;
#pragma unroll
    for (int s = 0; s < 2; ++s) {
      short8 af[4], bfr[4];
#pragma unroll
      for (int i = 0; i < 4; ++i) {
        int row = i * 16 + lm;
        int c = (s * 4 + lk) ^ (row & 7);
        af[i] = *(const short8*)&As[row * 64 + c * 8];
      }
#pragma unroll
      for (int j = 0; j < 4; ++j) {
        int row = wc + j * 16 + lm;
        int c = (s * 4 + lk) ^ (row & 7);
        bfr[j] = *(const short8*)&Bs[row * 64 + c * 8];
      }
#pragma unroll
      for (int i = 0; i < 4; ++i)
#pragma unroll
        for (int j = 0; j < 4; ++j)
          acc[i][j] = __builtin_amdgcn_mfma_f32_16x16x32_bf16(af[i], bfr[j], acc[i][j], 0, 0, 0);
    }
    __builtin_amdgcn_s_barrier();
  }

  {
    constexpr int LDC = 272;
    US* Cs = shm;
#pragma unroll
    for (int i = 0; i < 4; ++i)
#pragma unroll
      for (int j = 0; j < 4; ++j) {
        int colg = wc + j * 16 + lm;
#pragma unroll
        for (int r = 0; r < 4; ++r)
          Cs[(i * 16 + lk * 4 + r) * LDC + colg] = f2bf(acc[i][j][r]);
      }
    __syncthreads();
#pragma unroll
    for (int c = 0; c < 8; ++c) {
      int idx = tid + c * 256;
      int row = idx >> 5;
      int ch = idx & 31;
      uint4 v = *(const uint4*)&Cs[row * LDC + ch * 8];
      if (bm + row < M) *(uint4*)&C[(size_t)(bm + row) * 256 + ch * 8] = v;
    }
  }
}

// ----------------- driver -----------------

extern "C" void kernel_launch(void* const* d_in, const int* in_sizes, int n_in,
                              void* d_out, int out_size, void* d_ws, size_t ws_size,
                              hipStream_t stream) {
  const float* x  = (const float*)d_in[0];
  const int* ei   = (const int*)d_in[1];
  const float* W1 = (const float*)d_in[2];
  const float* b1 = (const float*)d_in[3];
  const float* W2 = (const float*)d_in[4];
  const float* b2 = (const float*)d_in[5];
  const float* W3 = (const float*)d_in[6];
  const float* b3 = (const float*)d_in[7];
  const float* W4 = (const float*)d_in[8];
  const float* b4 = (const float*)d_in[9];
  float* outp = (float*)d_out;

  const int N = N_NODES, E = N_EDGES;
  const int* row = ei;
  const int* col = ei + E;

  US* Ab = (US*)d_ws;                         // [N,256] bf16 ping
  US* Bb = Ab + (size_t)N * 256;              // [N,256] bf16 pong
  US* B64 = Bb + (size_t)N * 256;             // [N,64] (G6)
  US* Hfin = B64 + (size_t)N * 64;            // (unused, kept for layout)
  float* dinv = (float*)(Hfin + (size_t)N * 64);
  int* cnt = (int*)(dinv + N);
  int* row_ptr = cnt + N;
  int* fill = row_ptr + N;
  int* bsums = fill + N;                      // [256]
  int2* srcs2 = (int2*)(bsums + 256);         // [E]
  US* Wt1 = (US*)(srcs2 + E);                 // [256,256] old layout
  US* Wt2c = Wt1 + 256 * 256;                 // [32][256][8] chunked
  US* Wt3c = Wt2c + 256 * 256;                // [32][64][8] chunked

  hipMemsetAsync(cnt, 0, N * sizeof(int), stream);
  pre0_kernel<<<1024, 256, 0, stream>>>(col, cnt, x, Ab, W1, W2, W3,
                                        Wt1, Wt2c, Wt3c);
  int nblk = (N + 255) / 256;
  scan_block_kernel<<<nblk, 256, 0, stream>>>(cnt, row_ptr, bsums, dinv, N);
  scan_top_kernel<<<1, 256, 0, stream>>>(bsums, nblk);
  scan_add_kernel<<<nblk, 256, 0, stream>>>(row_ptr, fill, bsums, N);
  fill_kernel<<<(E + 255) / 256, 256, 0, stream>>>(row, col, fill, srcs2, dinv, E);

  int nf = (N + 31) / 32;   // 1563
  gemm256_kernel<<<(N + 63) / 64, 256, 0, stream>>>(Ab, Wt1, Bb, N);       // G1
  fused_ag256_kernel<<<nf, 256, 0, stream>>>(Bb, Ab, row_ptr, cnt, srcs2, dinv, b1, Wt2c, N);  // G2
  fused_ag256_kernel<<<nf, 256, 0, stream>>>(Ab, Bb, row_ptr, cnt, srcs2, dinv, b2, Wt2c, N);  // G3
  fused_ag256_kernel<<<nf, 256, 0, stream>>>(Bb, Ab, row_ptr, cnt, srcs2, dinv, b2, Wt2c, N);  // G4
  fused_ag256_kernel<<<nf, 256, 0, stream>>>(Ab, Bb, row_ptr, cnt, srcs2, dinv, b2, Wt2c, N);  // G5
  fused_ag64_kernel<<<nf, 256, 0, stream>>>(Bb, B64, row_ptr, cnt, srcs2, dinv, b2, Wt3c, N);  // G6
  aggfinal_kernel<<<(N + 15) / 16, 256, 0, stream>>>(B64, outp, row_ptr, cnt, srcs2, dinv,
                                                     b3, W4, b4, N);
}

// Round 4
// 601.982 us; speedup vs baseline: 1.1992x; 1.1992x over previous
//
#include <hip/hip_runtime.h>
#include <hip/hip_bf16.h>
#include <math.h>

#define N_NODES 50000
#define N_EDGES 800000
#define GK 256
// XCD chunking: 6272 nodes/chunk (= 98 gemm256-tiles x 64 = 49 gemm64-tiles x 128
// = 1568 agg-blocks x 4). 8 chunks cover 50176 >= N.
#define AGG_BLKS_PER_XCD 1568
#define G256_TILES_PER_XCD 98
#define G64_TILES_PER_XCD 49

typedef unsigned short US;
typedef __attribute__((ext_vector_type(8))) short short8;
typedef __attribute__((ext_vector_type(4))) float floatx4;
typedef __attribute__((address_space(1))) const void* gptr_t;
typedef __attribute__((address_space(3))) void* lptr_t;

static __device__ __forceinline__ float bflo(unsigned int u) {
  union { unsigned int i; float f; } c; c.i = u << 16; return c.f;
}
static __device__ __forceinline__ float bfhi(unsigned int u) {
  union { unsigned int i; float f; } c; c.i = u & 0xffff0000u; return c.f;
}
static __device__ __forceinline__ float bf2f(US u) {
  union { unsigned int i; float f; } c; c.i = ((unsigned int)u) << 16; return c.f;
}
static __device__ __forceinline__ US f2bf(float f) {  // round-to-nearest-even
  union { float f; unsigned int i; } c; c.f = f;
  unsigned int x = c.i;
  return (US)((x + 0x7fffu + ((x >> 16) & 1u)) >> 16);
}

// ----------------- preprocessing -----------------

__global__ void pre0_kernel(const int* __restrict__ col, int* __restrict__ cnt,
                            const float* __restrict__ x, US* __restrict__ xb,
                            const float* __restrict__ W1, const float* __restrict__ W2,
                            const float* __restrict__ W3,
                            US* __restrict__ Wt1, US* __restrict__ Wt2,
                            US* __restrict__ Wt3) {
  int gt = blockIdx.x * 256 + threadIdx.x;
  int gs = gridDim.x * 256;
  for (int e = gt; e < N_EDGES; e += gs) atomicAdd(&cnt[col[e]], 1);
  for (int i = gt; i < N_NODES * 64; i += gs) {   // x: 12.8M elems / 4
    float4 v = *(const float4*)(x + (size_t)i * 4);
    US o[4] = { f2bf(v.x), f2bf(v.y), f2bf(v.z), f2bf(v.w) };
    *(ushort4*)(xb + (size_t)i * 4) = *(ushort4*)o;
  }
  for (int idx = gt; idx < 147456; idx += gs) {
    if (idx < 65536) {
      int k = idx >> 8, n = idx & 255;
      Wt1[n * 256 + k] = f2bf(W1[idx]);
    } else if (idx < 131072) {
      int i = idx - 65536, k = i >> 8, n = i & 255;
      Wt2[n * 256 + k] = f2bf(W2[i]);
    } else {
      int i = idx - 131072, k = i >> 6, n = i & 63;
      Wt3[n * 256 + k] = f2bf(W3[i]);
    }
  }
}

__global__ void scan_block_kernel(const int* __restrict__ in, int* __restrict__ out,
                                  int* __restrict__ bsums, float* __restrict__ dinv, int n) {
  __shared__ int s[256];
  int gid = blockIdx.x * 256 + threadIdx.x;
  int v = (gid < n) ? in[gid] : 0;
  if (gid < n) dinv[gid] = 1.0f / sqrtf((float)(v + 1));  // +1 self-loop
  s[threadIdx.x] = v;
  __syncthreads();
  for (int off = 1; off < 256; off <<= 1) {
    int t = (threadIdx.x >= off) ? s[threadIdx.x - off] : 0;
    __syncthreads();
    s[threadIdx.x] += t;
    __syncthreads();
  }
  if (gid < n) out[gid] = s[threadIdx.x] - v;  // exclusive
  if (threadIdx.x == 255) bsums[blockIdx.x] = s[255];
}

__global__ void scan_top_kernel(int* __restrict__ bsums, int n) {
  __shared__ int s[256];
  int v = (threadIdx.x < n) ? bsums[threadIdx.x] : 0;
  s[threadIdx.x] = v;
  __syncthreads();
  for (int off = 1; off < 256; off <<= 1) {
    int t = (threadIdx.x >= off) ? s[threadIdx.x - off] : 0;
    __syncthreads();
    s[threadIdx.x] += t;
    __syncthreads();
  }
  if (threadIdx.x < n) bsums[threadIdx.x] = s[threadIdx.x] - v;
}

__global__ void scan_add_kernel(int* __restrict__ row_ptr, int* __restrict__ fill,
                                const int* __restrict__ bsums, int n) {
  int gid = blockIdx.x * 256 + threadIdx.x;
  if (gid < n) {
    int v = row_ptr[gid] + bsums[blockIdx.x];
    row_ptr[gid] = v;
    fill[gid] = v;
  }
}

__global__ void fill_kernel(const int* __restrict__ row, const int* __restrict__ col,
                            int* __restrict__ fill, int2* __restrict__ srcs2,
                            const float* __restrict__ dinv, int E) {
  int e = blockIdx.x * blockDim.x + threadIdx.x;
  if (e < E) {
    int d = col[e];
    int r = row[e];
    int pos = atomicAdd(&fill[d], 1);
    srcs2[pos] = make_int2(r, __float_as_int(dinv[r]));
  }
}

// ----------------- gemm256: C[M,256] = A[M,256] @ Wt[256,256]^T -----------------
// R4: 64M x 128N tiles, 48KB LDS -> 3 blocks/CU; grid 1568 = exactly 2 rounds
// (was 80KB/2 blocks/CU + 53%-empty tail round). Chunk-XCD swizzle co-locates
// A-reads with the agg blocks that wrote them. Sync = proven R2 counted-vmcnt dbuf.

__global__ __launch_bounds__(256) void gemm256_kernel(
    const US* __restrict__ A, const US* __restrict__ Wt,
    US* __restrict__ C, int M) {
  __shared__ __align__(16) US shm[24576];      // 48KB
  // As0 [0,4096) As1 [4096,8192) Bs0 [8192,16384) Bs1 [16384,24576)
  int tid = threadIdx.x;
  int L = blockIdx.x;
  int xcd = L & 7, kk = L >> 3;
  int bmIdx = xcd * G256_TILES_PER_XCD + (kk >> 1);
  int bm = bmIdx * 64;
  int bn = (kk & 1) * 128;
  int lane = tid & 63;
  int w = tid >> 6;
  int wc = w * 32;
  int lm = lane & 15, lk = lane >> 4;
  int lr = lane >> 3, lc = lane & 7;
  int gc = lc ^ lr;

  floatx4 zero = {0.f, 0.f, 0.f, 0.f};
  floatx4 acc[4][2];
#pragma unroll
  for (int i = 0; i < 4; ++i)
#pragma unroll
    for (int j = 0; j < 2; ++j) acc[i][j] = zero;

  // 6 global_load_lds per K-tile (A: 2, B: 4), count exact via clamp
  auto issue = [&](int k, int b) {
    int k0 = k * 64;
    US* As = shm + b * 4096;
    US* Bs = shm + 8192 + b * 8192;
#pragma unroll
    for (int i = 0; i < 2; ++i) {
      int rbase = i * 32 + w * 8;
      int r = min(bm + rbase + lr, M - 1);
      const US* ga = A + (size_t)r * GK + k0 + gc * 8;
      __builtin_amdgcn_global_load_lds((gptr_t)(const void*)ga,
                                       (lptr_t)(void*)&As[rbase * 64], 16, 0, 0);
    }
#pragma unroll
    for (int i = 0; i < 4; ++i) {
      int rbase = i * 32 + w * 8;
      int r = bn + rbase + lr;                 // Wt rows [bn, bn+128)
      const US* gb = Wt + (size_t)r * GK + k0 + gc * 8;
      __builtin_amdgcn_global_load_lds((gptr_t)(const void*)gb,
                                       (lptr_t)(void*)&Bs[rbase * 64], 16, 0, 0);
    }
  };

  issue(0, 0);
#pragma unroll
  for (int k = 0; k < 4; ++k) {
    if (k < 3) {
      issue(k + 1, (k + 1) & 1);
      asm volatile("s_waitcnt vmcnt(6)" ::: "memory");   // tile-k done, k+1 in flight
    } else {
      asm volatile("s_waitcnt vmcnt(0)" ::: "memory");
    }
    __builtin_amdgcn_sched_barrier(0);
    __builtin_amdgcn_s_barrier();
    const US* As = shm + (k & 1) * 4096;
    const US* Bs = shm + 8192 + (k & 1) * 8192;
#pragma unroll
    for (int s = 0; s < 2; ++s) {
      short8 af[4], bfr[2];
#pragma unroll
      for (int i = 0; i < 4; ++i) {
        int row = i * 16 + lm;
        int c = (s * 4 + lk) ^ (row & 7);
        af[i] = *(const short8*)&As[row * 64 + c * 8];
      }
#pragma unroll
      for (int j = 0; j < 2; ++j) {
        int row = wc + j * 16 + lm;
        int c = (s * 4 + lk) ^ (row & 7);
        bfr[j] = *(const short8*)&Bs[row * 64 + c * 8];
      }
#pragma unroll
      for (int i = 0; i < 4; ++i)
#pragma unroll
        for (int j = 0; j < 2; ++j)
          acc[i][j] = __builtin_amdgcn_mfma_f32_16x16x32_bf16(af[i], bfr[j], acc[i][j], 0, 0, 0);
    }
    __builtin_amdgcn_s_barrier();
  }

  // epilogue: LDS stage (64 rows x 128 cols, pad 8) -> coalesced 16B stores
  {
    constexpr int LDC = 136;
    US* Cs = shm;                              // 64*136 = 8704 US <= 24576
#pragma unroll
    for (int i = 0; i < 4; ++i)
#pragma unroll
      for (int j = 0; j < 2; ++j) {
        int colg = wc + j * 16 + lm;
#pragma unroll
        for (int r = 0; r < 4; ++r)
          Cs[(i * 16 + lk * 4 + r) * LDC + colg] = f2bf(acc[i][j][r]);
      }
    __syncthreads();
#pragma unroll
    for (int c = 0; c < 4; ++c) {              // 1024 = 64 rows x 16 chunks
      int idx = tid + c * 256;
      int row = idx >> 4;
      int ch = idx & 15;
      uint4 v = *(const uint4*)&Cs[row * LDC + ch * 8];
      if (bm + row < M) *(uint4*)&C[(size_t)(bm + row) * 256 + bn + ch * 8] = v;
    }
  }
}

// ----------------- gemm64: C[M,64] = A[M,256] @ Wt3[64,256]^T -----------------
// R2 pipeline (proven), + chunk-XCD swizzle for local A-reads.

__global__ __launch_bounds__(256) void gemm64_kernel(
    const US* __restrict__ A, const US* __restrict__ Wt,
    US* __restrict__ C, int M) {
  __shared__ __align__(16) US shm[24576];      // 48KB
  int tid = threadIdx.x;
  int L = blockIdx.x;
  int b = (L & 7) * G64_TILES_PER_XCD + (L >> 3);
  int bm = b * 128;
  int lane = tid & 63;
  int w = tid >> 6;
  int wr = w * 32;
  int lm = lane & 15, lk = lane >> 4;
  int lr = lane >> 3, lc = lane & 7;
  int gc = lc ^ lr;

  floatx4 zero = {0.f, 0.f, 0.f, 0.f};
  floatx4 acc[2][4];
#pragma unroll
  for (int i = 0; i < 2; ++i)
#pragma unroll
    for (int j = 0; j < 4; ++j) acc[i][j] = zero;

  auto issue = [&](int k, int bb) {
    int k0 = k * 64;
    US* As = shm + bb * 8192;
    US* Bs = shm + 16384 + bb * 4096;
#pragma unroll
    for (int i = 0; i < 4; ++i) {
      int rbase = i * 32 + w * 8;
      int r = min(bm + rbase + lr, M - 1);
      const US* ga = A + (size_t)r * GK + k0 + gc * 8;
      __builtin_amdgcn_global_load_lds((gptr_t)(const void*)ga,
                                       (lptr_t)(void*)&As[rbase * 64], 16, 0, 0);
    }
#pragma unroll
    for (int i = 0; i < 2; ++i) {
      int rbase = i * 32 + w * 8;
      int r = rbase + lr;
      const US* gb = Wt + (size_t)r * GK + k0 + gc * 8;
      __builtin_amdgcn_global_load_lds((gptr_t)(const void*)gb,
                                       (lptr_t)(void*)&Bs[rbase * 64], 16, 0, 0);
    }
  };

  issue(0, 0);
#pragma unroll
  for (int k = 0; k < 4; ++k) {
    if (k < 3) {
      issue(k + 1, (k + 1) & 1);
      asm volatile("s_waitcnt vmcnt(6)" ::: "memory");
    } else {
      asm volatile("s_waitcnt vmcnt(0)" ::: "memory");
    }
    __builtin_amdgcn_sched_barrier(0);
    __builtin_amdgcn_s_barrier();
    const US* As = shm + (k & 1) * 8192;
    const US* Bs = shm + 16384 + (k & 1) * 4096;
#pragma unroll
    for (int s = 0; s < 2; ++s) {
      short8 af[2], bfr[4];
#pragma unroll
      for (int i = 0; i < 2; ++i) {
        int row = wr + i * 16 + lm;
        int c = (s * 4 + lk) ^ (row & 7);
        af[i] = *(const short8*)&As[row * 64 + c * 8];
      }
#pragma unroll
      for (int j = 0; j < 4; ++j) {
        int row = j * 16 + lm;
        int c = (s * 4 + lk) ^ (row & 7);
        bfr[j] = *(const short8*)&Bs[row * 64 + c * 8];
      }
#pragma unroll
      for (int i = 0; i < 2; ++i)
#pragma unroll
        for (int j = 0; j < 4; ++j)
          acc[i][j] = __builtin_amdgcn_mfma_f32_16x16x32_bf16(af[i], bfr[j], acc[i][j], 0, 0, 0);
    }
    __builtin_amdgcn_s_barrier();
  }

  {
    constexpr int LDC = 72;
    US* Cs = shm;                              // 128*72 = 9216 US
#pragma unroll
    for (int i = 0; i < 2; ++i)
#pragma unroll
      for (int j = 0; j < 4; ++j) {
        int colg = j * 16 + lm;
#pragma unroll
        for (int r = 0; r < 4; ++r)
          Cs[(wr + i * 16 + lk * 4 + r) * LDC + colg] = f2bf(acc[i][j][r]);
      }
    __syncthreads();
#pragma unroll
    for (int c = 0; c < 4; ++c) {
      int idx = tid + c * 256;
      int row = idx >> 3;       // 0..127
      int ch = idx & 7;         // 0..7
      uint4 v = *(const uint4*)&Cs[row * LDC + ch * 8];
      if (bm + row < M) *(uint4*)&C[(size_t)(bm + row) * 64 + ch * 8] = v;
    }
  }
}

// ----------------- pull aggregation (R2-proven structure + chunk-XCD swizzle) ----
// Rate-limited at ~3.7 TB/s on the L2-miss path (A/B-confirmed R0/R1/R3).
// Chunk swizzle makes h-writes land in the L2 of the XCD whose gemm will read them.

template <bool RELU>
__global__ __launch_bounds__(256) void agg256_kernel(
    const US* __restrict__ t, US* __restrict__ out,
    const int* __restrict__ row_ptr, const int* __restrict__ cnt,
    const int2* __restrict__ srcs2, const float* __restrict__ dinv,
    const float* __restrict__ bias) {
  int L = blockIdx.x;
  int jg = (L & 7) * AGG_BLKS_PER_XCD + (L >> 3);
  int j = jg * 4 + (threadIdx.x >> 6);
  if (j >= N_NODES) return;                    // wave-uniform, no barriers below
  int lane = threadIdx.x & 63;
  int h = lane & 31;
  int eidx = lane >> 5;
  int base = h * 8;
  int start = row_ptr[j];
  int n = cnt[j];
  float a[8];
#pragma unroll
  for (int k = 0; k < 8; ++k) a[k] = 0.f;

  int i = 0;
  for (; i + 7 < n; i += 8) {
    int2 e0 = srcs2[start + i + 0 + eidx];
    int2 e1 = srcs2[start + i + 2 + eidx];
    int2 e2 = srcs2[start + i + 4 + eidx];
    int2 e3 = srcs2[start + i + 6 + eidx];
    uint4 v0 = *(const uint4*)(t + (size_t)e0.x * 256 + base);
    uint4 v1 = *(const uint4*)(t + (size_t)e1.x * 256 + base);
    uint4 v2 = *(const uint4*)(t + (size_t)e2.x * 256 + base);
    uint4 v3 = *(const uint4*)(t + (size_t)e3.x * 256 + base);
    float w0 = __int_as_float(e0.y), w1 = __int_as_float(e1.y);
    float w2 = __int_as_float(e2.y), w3 = __int_as_float(e3.y);
    a[0] += bflo(v0.x) * w0; a[1] += bfhi(v0.x) * w0;
    a[2] += bflo(v0.y) * w0; a[3] += bfhi(v0.y) * w0;
    a[4] += bflo(v0.z) * w0; a[5] += bfhi(v0.z) * w0;
    a[6] += bflo(v0.w) * w0; a[7] += bfhi(v0.w) * w0;
    a[0] += bflo(v1.x) * w1; a[1] += bfhi(v1.x) * w1;
    a[2] += bflo(v1.y) * w1; a[3] += bfhi(v1.y) * w1;
    a[4] += bflo(v1.z) * w1; a[5] += bfhi(v1.z) * w1;
    a[6] += bflo(v1.w) * w1; a[7] += bfhi(v1.w) * w1;
    a[0] += bflo(v2.x) * w2; a[1] += bfhi(v2.x) * w2;
    a[2] += bflo(v2.y) * w2; a[3] += bfhi(v2.y) * w2;
    a[4] += bflo(v2.z) * w2; a[5] += bfhi(v2.z) * w2;
    a[6] += bflo(v2.w) * w2; a[7] += bfhi(v2.w) * w2;
    a[0] += bflo(v3.x) * w3; a[1] += bfhi(v3.x) * w3;
    a[2] += bflo(v3.y) * w3; a[3] += bfhi(v3.y) * w3;
    a[4] += bflo(v3.z) * w3; a[5] += bfhi(v3.z) * w3;
    a[6] += bflo(v3.w) * w3; a[7] += bfhi(v3.w) * w3;
  }
  for (; i < n; i += 2) {
    int idx = i + eidx;
    int cl = min(idx, n - 1);
    int2 e = srcs2[start + cl];
    float w = (idx < n) ? __int_as_float(e.y) : 0.f;
    uint4 v = *(const uint4*)(t + (size_t)e.x * 256 + base);
    a[0] += bflo(v.x) * w; a[1] += bfhi(v.x) * w;
    a[2] += bflo(v.y) * w; a[3] += bfhi(v.y) * w;
    a[4] += bflo(v.z) * w; a[5] += bfhi(v.z) * w;
    a[6] += bflo(v.w) * w; a[7] += bfhi(v.w) * w;
  }
#pragma unroll
  for (int k = 0; k < 8; ++k) a[k] += __shfl_xor(a[k], 32, 64);

  float dj = dinv[j];
  uint4 vj = *(const uint4*)(t + (size_t)j * 256 + base);
  float4 bv0 = *(const float4*)(bias + base);
  float4 bv1 = *(const float4*)(bias + base + 4);
  float r[8];
  r[0] = (a[0] + bflo(vj.x) * dj) * dj + bv0.x;
  r[1] = (a[1] + bfhi(vj.x) * dj) * dj + bv0.y;
  r[2] = (a[2] + bflo(vj.y) * dj) * dj + bv0.z;
  r[3] = (a[3] + bfhi(vj.y) * dj) * dj + bv0.w;
  r[4] = (a[4] + bflo(vj.z) * dj) * dj + bv1.x;
  r[5] = (a[5] + bfhi(vj.z) * dj) * dj + bv1.y;
  r[6] = (a[6] + bflo(vj.w) * dj) * dj + bv1.z;
  r[7] = (a[7] + bfhi(vj.w) * dj) * dj + bv1.w;
  if (RELU) {
#pragma unroll
    for (int k = 0; k < 8; ++k) r[k] = fmaxf(r[k], 0.f);
  }
  if (lane < 32) {
    US o[8];
#pragma unroll
    for (int k = 0; k < 8; ++k) o[k] = f2bf(r[k]);
    *(uint4*)(out + (size_t)j * 256 + base) = *(const uint4*)o;
  }
}

// ----------------- fused agg64 + final dense + sigmoid (R3, passed) -----------------

__global__ __launch_bounds__(256) void aggfinal_kernel(
    const US* __restrict__ t, float* __restrict__ out,
    const int* __restrict__ row_ptr, const int* __restrict__ cnt,
    const int2* __restrict__ srcs2, const float* __restrict__ dinv,
    const float* __restrict__ b3, const float* __restrict__ W4,
    const float* __restrict__ b4, int M) {
  __shared__ float W4s[4096];
  __shared__ float b4s[64];
  __shared__ float hbuf[4][64];
  int tid = threadIdx.x;
#pragma unroll
  for (int it = 0; it < 16; ++it) W4s[it * 256 + tid] = W4[it * 256 + tid];
  if (tid < 64) b4s[tid] = b4[tid];
  __syncthreads();

  int wv = tid >> 6, lane = tid & 63;
  int g = lane & 15, eidx = lane >> 4;
  int base = g * 4;
#pragma unroll 1
  for (int q = 0; q < 4; ++q) {
    int j = blockIdx.x * 16 + wv * 4 + q;
    if (j >= M) break;
    int start = row_ptr[j];
    int n = cnt[j];
    float a[4] = {0.f, 0.f, 0.f, 0.f};
    int i = 0;
    for (; i + 7 < n; i += 8) {
      int2 e0 = srcs2[start + i + eidx];
      int2 e1 = srcs2[start + i + 4 + eidx];
      uint2 v0 = *(const uint2*)(t + (size_t)e0.x * 64 + base);
      uint2 v1 = *(const uint2*)(t + (size_t)e1.x * 64 + base);
      float w0 = __int_as_float(e0.y), w1 = __int_as_float(e1.y);
      a[0] += bflo(v0.x) * w0; a[1] += bfhi(v0.x) * w0;
      a[2] += bflo(v0.y) * w0; a[3] += bfhi(v0.y) * w0;
      a[0] += bflo(v1.x) * w1; a[1] += bfhi(v1.x) * w1;
      a[2] += bflo(v1.y) * w1; a[3] += bfhi(v1.y) * w1;
    }
    for (; i < n; i += 4) {
      int idx = i + eidx;
      int cl = min(idx, n - 1);
      int2 e = srcs2[start + cl];
      float w0 = (idx < n) ? __int_as_float(e.y) : 0.f;
      uint2 v = *(const uint2*)(t + (size_t)e.x * 64 + base);
      a[0] += bflo(v.x) * w0; a[1] += bfhi(v.x) * w0;
      a[2] += bflo(v.y) * w0; a[3] += bfhi(v.y) * w0;
    }
#pragma unroll
    for (int k = 0; k < 4; ++k) {
      a[k] += __shfl_xor(a[k], 16, 64);
      a[k] += __shfl_xor(a[k], 32, 64);
    }
    float dj = dinv[j];
    uint2 vj = *(const uint2*)(t + (size_t)j * 64 + base);
    float4 bv = *(const float4*)(b3 + base);
    float h0 = (a[0] + bflo(vj.x) * dj) * dj + bv.x;
    float h1 = (a[1] + bfhi(vj.x) * dj) * dj + bv.y;
    float h2 = (a[2] + bflo(vj.y) * dj) * dj + bv.z;
    float h3 = (a[3] + bfhi(vj.y) * dj) * dj + bv.w;
    if (lane < 16) {
      float4 hv = make_float4(h0, h1, h2, h3);
      *(float4*)&hbuf[wv][base] = hv;
    }
    asm volatile("s_waitcnt lgkmcnt(0)" ::: "memory");
    float acc = b4s[lane];
#pragma unroll 8
    for (int k = 0; k < 64; ++k) acc += hbuf[wv][k] * W4s[k * 64 + lane];
    out[(size_t)j * 64 + lane] = 1.0f / (1.0f + expf(-acc));
  }
}

// ----------------- driver -----------------

extern "C" void kernel_launch(void* const* d_in, const int* in_sizes, int n_in,
                              void* d_out, int out_size, void* d_ws, size_t ws_size,
                              hipStream_t stream) {
  const float* x  = (const float*)d_in[0];
  const int* ei   = (const int*)d_in[1];
  const float* W1 = (const float*)d_in[2];
  const float* b1 = (const float*)d_in[3];
  const float* W2 = (const float*)d_in[4];
  const float* b2 = (const float*)d_in[5];
  const float* W3 = (const float*)d_in[6];
  const float* b3 = (const float*)d_in[7];
  const float* W4 = (const float*)d_in[8];
  const float* b4 = (const float*)d_in[9];
  float* outp = (float*)d_out;

  const int N = N_NODES, E = N_EDGES;
  const int* row = ei;
  const int* col = ei + E;

  US* Ab = (US*)d_ws;                         // [N,256] bf16 ping
  US* Bb = Ab + (size_t)N * 256;              // [N,256] bf16 pong
  US* B64 = Bb + (size_t)N * 256;             // [N,64] (G6)
  US* Hfin = B64 + (size_t)N * 64;            // (unused, layout kept)
  float* dinv = (float*)(Hfin + (size_t)N * 64);
  int* cnt = (int*)(dinv + N);
  int* row_ptr = cnt + N;
  int* fill = row_ptr + N;
  int* bsums = fill + N;                      // [256]
  int2* srcs2 = (int2*)(bsums + 256);         // [E]
  US* Wt1 = (US*)(srcs2 + E);                 // [256,256]
  US* Wt2 = Wt1 + 256 * 256;                  // [256,256]
  US* Wt3 = Wt2 + 256 * 256;                  // [64,256]

  hipMemsetAsync(cnt, 0, N * sizeof(int), stream);
  pre0_kernel<<<1024, 256, 0, stream>>>(col, cnt, x, Ab, W1, W2, W3,
                                        Wt1, Wt2, Wt3);
  int nblk = (N + 255) / 256;
  scan_block_kernel<<<nblk, 256, 0, stream>>>(cnt, row_ptr, bsums, dinv, N);
  scan_top_kernel<<<1, 256, 0, stream>>>(bsums, nblk);
  scan_add_kernel<<<nblk, 256, 0, stream>>>(row_ptr, fill, bsums, N);
  fill_kernel<<<(E + 255) / 256, 256, 0, stream>>>(row, col, fill, srcs2, dinv, E);

  const int g256 = 8 * G256_TILES_PER_XCD * 2;   // 1568
  const int gagg = 8 * AGG_BLKS_PER_XCD;         // 12544
  const int g64g = 8 * G64_TILES_PER_XCD;        // 392

  gemm256_kernel<<<g256, 256, 0, stream>>>(Ab, Wt1, Bb, N);
  agg256_kernel<true><<<gagg, 256, 0, stream>>>(Bb, Ab, row_ptr, cnt, srcs2, dinv, b1);
  for (int l = 0; l < 4; ++l) {
    gemm256_kernel<<<g256, 256, 0, stream>>>(Ab, Wt2, Bb, N);
    agg256_kernel<true><<<gagg, 256, 0, stream>>>(Bb, Ab, row_ptr, cnt, srcs2, dinv, b2);
  }
  gemm64_kernel<<<g64g, 256, 0, stream>>>(Ab, Wt3, B64, N);
  aggfinal_kernel<<<(N + 15) / 16, 256, 0, stream>>>(B64, outp, row_ptr, cnt, srcs2, dinv,
                                                     b3, W4, b4, N);
}